// Round 3
// baseline (204.363 us; speedup 1.0000x reference)
//
#include <hip/hip_runtime.h>
#include <math.h>

#define DIM    2048
#define BATCH  256
#define PN     56         // PATCH_NUM - MASK_NUM
#define HALF   1024       // DIM/2 columns per block
#define CHUNK  256        // columns per LDS-staged chunk
#define NCHUNK 4          // HALF / CHUNK
#define NBLK   512        // BATCH * 2 halves
constexpr float KD_T = 4.0f;

// ---------------- reduction helpers (wave = 64) ----------------
__device__ __forceinline__ float wave_sum(float v) {
#pragma unroll
    for (int o = 32; o > 0; o >>= 1) v += __shfl_xor(v, o, 64);
    return v;
}
__device__ __forceinline__ double wave_sum_d(double v) {
#pragma unroll
    for (int o = 32; o > 0; o >>= 1) v += __shfl_xor(v, o, 64);
    return v;
}

// ---------------- fused bar + dil + dcl (single HBM pass over ebp) ---------
// block = (b, half). Per 256-col chunk:
//   pass A: thread t owns column base+t; streams 56 p values (coalesced),
//           accumulates bar in-register, stages chunk to LDS, dil partials.
//   pass B: wave wv owns p = wv*14+i; ds_read_b128 conflict-free; 4 sym-KL
//           sums per p kept in 56 regs, wave-reduced ONCE after chunk loop.
__global__ void __launch_bounds__(256) fused_kernel(const float* __restrict__ ebg,
                                                    const float* __restrict__ ebp,
                                                    float* __restrict__ pdcl,  // [NBLK][PN][4]
                                                    float* __restrict__ pdil)  // [NBLK][4]
{
    __shared__ float ebp_s[PN * CHUNK];   // 57344 B
    __shared__ float bar_s[CHUNK];
    __shared__ float redl[4][4];

    const int t    = threadIdx.x;
    const int lane = t & 63;
    const int wv   = t >> 6;
    const int bid  = blockIdx.x;
    const int b    = bid >> 1;
    const int half = bid & 1;
    const float invT = 1.0f / KD_T;

    float acc[14][4];
#pragma unroll
    for (int i = 0; i < 14; ++i)
#pragma unroll
        for (int j = 0; j < 4; ++j) acc[i][j] = 0.f;

    float dss = 0.f, dts = 0.f, dt1 = 0.f, dt2 = 0.f;

    const size_t browoff = (size_t)b * DIM + (size_t)half * HALF;

    for (int c = 0; c < NCHUNK; ++c) {
        const int base = c * CHUNK;

        // ---- pass A ----
        const float* ep = ebp + browoff + base + t;
        float bsum = 0.f;
#pragma unroll 14
        for (int p = 0; p < PN; ++p) {
            float v = ep[(size_t)p * (BATCH * DIM)];
            bsum += v;
            ebp_s[p * CHUNK + t] = v;
        }
        float barv = bsum * (1.0f / PN);
        bar_s[t] = barv;
        {   // dil partial at column base+t
            float g = ebg[browoff + base + t];
            float s = g * invT, tv = barv * invT;
            float es = __expf(s), et = __expf(tv);
            float dd = tv - s;
            dss += es; dts += et;
            dt1 = fmaf(es, dd, dt1);
            dt2 = fmaf(et, dd, dt2);
        }
        __syncthreads();

        // ---- pass B ----
        const float4 g4 = *(const float4*)(ebg + browoff + base + lane * 4);
        const float4 m4 = *(const float4*)(bar_s + lane * 4);
        const float gs[4] = {g4.x, g4.y, g4.z, g4.w};
        const float ms[4] = {m4.x, m4.y, m4.z, m4.w};
#pragma unroll
        for (int i = 0; i < 14; ++i) {
            const int p = wv * 14 + i;
            float4 e = *(const float4*)(ebp_s + p * CHUNK + lane * 4);
            float es_[4] = {e.x, e.y, e.z, e.w};
#pragma unroll
            for (int k = 0; k < 4; ++k) {
                float dg = gs[k] - es_[k];
                float db = ms[k] - es_[k];
                float a  = dg * dg * invT;
                float cc = db * db * invT;
                float ea = __expf(a), ec = __expf(cc);
                float d  = cc - a;
                acc[i][0] += ea;
                acc[i][1] += ec;
                acc[i][2] = fmaf(ea, d, acc[i][2]);
                acc[i][3] = fmaf(ec, d, acc[i][3]);
            }
        }
        __syncthreads();
    }

    // ---- dcl: one wave-reduction per owned p, written once ----
#pragma unroll
    for (int i = 0; i < 14; ++i) {
        float a0 = wave_sum(acc[i][0]);
        float a1 = wave_sum(acc[i][1]);
        float a2 = wave_sum(acc[i][2]);
        float a3 = wave_sum(acc[i][3]);
        if (lane == 0) {
            float* q = pdcl + ((size_t)bid * PN + wv * 14 + i) * 4;
            q[0] = a0; q[1] = a1; q[2] = a2; q[3] = a3;
        }
    }
    // ---- dil: block reduction ----
    dss = wave_sum(dss); dts = wave_sum(dts);
    dt1 = wave_sum(dt1); dt2 = wave_sum(dt2);
    if (lane == 0) { redl[wv][0] = dss; redl[wv][1] = dts; redl[wv][2] = dt1; redl[wv][3] = dt2; }
    __syncthreads();
    if (t == 0) {
        float* q = pdil + (size_t)bid * 4;
#pragma unroll
        for (int j = 0; j < 4; ++j)
            q[j] = redl[0][j] + redl[1][j] + redl[2][j] + redl[3][j];
    }
}

// ---------------- finalize: combine halves in double, emit outputs --------
__global__ void __launch_bounds__(256) finalize_kernel(const float* __restrict__ pdcl,
                                                       const float* __restrict__ pdil,
                                                       float* __restrict__ out)
{
    __shared__ double sdc[4], sdl[4];
    const int t = threadIdx.x, lane = t & 63, wv = t >> 6;
    const int b = t;   // thread t owns batch row b

    double dsum = 0.0;
    for (int p = 0; p < PN; ++p) {
        const float* q0 = pdcl + ((size_t)(b * 2 + 0) * PN + p) * 4;
        const float* q1 = pdcl + ((size_t)(b * 2 + 1) * PN + p) * 4;
        double asum = (double)q0[0] + q1[0];
        double csum = (double)q0[1] + q1[1];
        double t1   = (double)q0[2] + q1[2];
        double t2   = (double)q0[3] + q1[3];
        dsum += t2 / csum - t1 / asum;
    }
    const float* r0 = pdil + (size_t)(b * 2 + 0) * 4;
    const float* r1 = pdil + (size_t)(b * 2 + 1) * 4;
    double ss = (double)r0[0] + r1[0];
    double ts = (double)r0[1] + r1[1];
    double u1 = (double)r0[2] + r1[2];
    double u2 = (double)r0[3] + r1[3];
    double lsum = u2 / ts - u1 / ss;

    dsum = wave_sum_d(dsum); lsum = wave_sum_d(lsum);
    if (lane == 0) { sdc[wv] = dsum; sdl[wv] = lsum; }
    __syncthreads();
    if (t == 0) {
        double kT2 = (double)KD_T * KD_T;
        out[0] = (float)((sdl[0] + sdl[1] + sdl[2] + sdl[3]) * (kT2 / DIM));
        out[1] = (float)((sdc[0] + sdc[1] + sdc[2] + sdc[3]) * (kT2 / DIM / PN));
    }
}

extern "C" void kernel_launch(void* const* d_in, const int* in_sizes, int n_in,
                              void* d_out, int out_size, void* d_ws, size_t ws_size,
                              hipStream_t stream) {
    const float* ebg = (const float*)d_in[0];
    const float* ebp = (const float*)d_in[1];
    // labels (d_in[2]) unused by the forward computation

    float* pdcl = (float*)d_ws;                              // NBLK*PN*4 floats = 448 KB
    float* pdil = pdcl + (size_t)NBLK * PN * 4;              // NBLK*4 floats = 8 KB

    fused_kernel<<<NBLK, 256, 0, stream>>>(ebg, ebp, pdcl, pdil);
    finalize_kernel<<<1, 256, 0, stream>>>(pdcl, pdil, (float*)d_out);
}

// Round 4
// 183.693 us; speedup vs baseline: 1.1125x; 1.1125x over previous
//
#include <hip/hip_runtime.h>
#include <math.h>

#define DIM    2048
#define BATCH  256
#define PN     56          // PATCH_NUM - MASK_NUM
#define CHUNK  128         // columns staged in LDS at a time
#define NCHUNK 4           // chunks per block
#define NQ     4           // column-quarters per batch row (DIM / QCOLS)
#define QCOLS  (CHUNK * NCHUNK)   // 512 cols per block
#define NBLK   (BATCH * NQ)       // 1024 blocks
constexpr float KD_T = 4.0f;

// ---------------- reduction helpers (wave = 64) ----------------
__device__ __forceinline__ float wave_sum(float v) {
#pragma unroll
    for (int o = 32; o > 0; o >>= 1) v += __shfl_xor(v, o, 64);
    return v;
}
__device__ __forceinline__ float half_sum(float v) {   // reduce within 32-lane half
#pragma unroll
    for (int o = 16; o > 0; o >>= 1) v += __shfl_xor(v, o, 64);
    return v;
}
__device__ __forceinline__ double wave_sum_d(double v) {
#pragma unroll
    for (int o = 32; o > 0; o >>= 1) v += __shfl_xor(v, o, 64);
    return v;
}

// ---------------- fused bar + dil + dcl (single HBM pass over ebp) ---------
// block = (b, quarter of D). Per 128-col chunk:
//   pass A: float4 staging, 8 p-rows per instruction, 7 loads in flight;
//           bar via lane^32 shuffle + 4-wave LDS combine.
//   pass B: half-wave per p-row (2 rows per wave per ds_read_b128; row
//           stride 512 B => 2-way bank aliasing = free). acc[7][4] regs.
// pdcl layout TRANSPOSED for coalesced finalize: [(p*BATCH + b)*NQ + q][4].
__global__ void __launch_bounds__(256) fused_kernel(const float* __restrict__ ebg,
                                                    const float* __restrict__ ebp,
                                                    float* __restrict__ pdcl,
                                                    float* __restrict__ pdil)  // [NBLK][4]
{
    __shared__ float  ebp_s[PN * CHUNK];   // 28672 B
    __shared__ float4 redbar[4][32];       // 2048 B
    __shared__ float  bar_s[CHUNK];        // 512 B
    __shared__ float  redl[4][4];

    const int t    = threadIdx.x;
    const int lane = t & 63;
    const int wv   = t >> 6;
    const int sub  = lane >> 5;            // half-wave id
    const int c32  = lane & 31;
    const int bid  = blockIdx.x;
    const int b    = bid >> 2;
    const int q    = bid & (NQ - 1);
    const float invT = 1.0f / KD_T;

    const size_t rowoff = (size_t)b * DIM + (size_t)q * QCOLS;

    float acc[7][4];                        // per-lane; row = wv*14 + 2*j + sub
#pragma unroll
    for (int j = 0; j < 7; ++j)
#pragma unroll
        for (int k = 0; k < 4; ++k) acc[j][k] = 0.f;

    float dss = 0.f, dts = 0.f, dt1 = 0.f, dt2 = 0.f;   // dil (threads t<128)

    for (int c = 0; c < NCHUNK; ++c) {
        const size_t cb = rowoff + (size_t)c * CHUNK;

        // ---- pass A: stage 56x128 chunk, 8 rows per instruction ----
        const int prow0 = t >> 5;          // 0..7
        const int cc4   = (t & 31) * 4;
        float4 vals[7];
#pragma unroll
        for (int it = 0; it < 7; ++it) {
            const int p = it * 8 + prow0;
            vals[it] = *(const float4*)(ebp + (size_t)p * (BATCH * DIM) + cb + cc4);
        }
        float4 bp = {0.f, 0.f, 0.f, 0.f};
#pragma unroll
        for (int it = 0; it < 7; ++it) {
            const int p = it * 8 + prow0;
            *(float4*)(ebp_s + p * CHUNK + cc4) = vals[it];
            bp.x += vals[it].x; bp.y += vals[it].y;
            bp.z += vals[it].z; bp.w += vals[it].w;
        }
        // combine the two half-waves (rows p and p+1 alternate across lane^32)
        bp.x += __shfl_xor(bp.x, 32, 64);
        bp.y += __shfl_xor(bp.y, 32, 64);
        bp.z += __shfl_xor(bp.z, 32, 64);
        bp.w += __shfl_xor(bp.w, 32, 64);
        if (c32 == lane) ;                 // no-op; clarity
        if (lane < 32) redbar[wv][lane] = bp;
        __syncthreads();
        if (t < 32) {
            float4 s0 = redbar[0][t], s1 = redbar[1][t],
                   s2 = redbar[2][t], s3 = redbar[3][t];
            float4 s;
            s.x = (s0.x + s1.x + s2.x + s3.x) * (1.0f / PN);
            s.y = (s0.y + s1.y + s2.y + s3.y) * (1.0f / PN);
            s.z = (s0.z + s1.z + s2.z + s3.z) * (1.0f / PN);
            s.w = (s0.w + s1.w + s2.w + s3.w) * (1.0f / PN);
            *(float4*)(bar_s + t * 4) = s;
        }
        __syncthreads();

        // ---- dil partials (threads 0..127, one column each) ----
        if (t < CHUNK) {
            float g = ebg[cb + t];
            float m = bar_s[t];
            float s = g * invT, tv = m * invT;
            float es = __expf(s), et = __expf(tv);
            float dd = tv - s;
            dss += es; dts += et;
            dt1 = fmaf(es, dd, dt1);
            dt2 = fmaf(et, dd, dt2);
        }

        // ---- pass B: half-wave per row, 14 rows per wave ----
        const float4 g4 = *(const float4*)(ebg + cb + c32 * 4);
        const float4 m4 = *(const float4*)(bar_s + c32 * 4);
        const float gs[4] = {g4.x, g4.y, g4.z, g4.w};
        const float ms[4] = {m4.x, m4.y, m4.z, m4.w};
#pragma unroll
        for (int j = 0; j < 7; ++j) {
            const int row = wv * 14 + 2 * j + sub;
            float4 e = *(const float4*)(ebp_s + row * CHUNK + c32 * 4);
            float es_[4] = {e.x, e.y, e.z, e.w};
#pragma unroll
            for (int k = 0; k < 4; ++k) {
                float dg = gs[k] - es_[k];
                float db = ms[k] - es_[k];
                float a  = dg * dg * invT;
                float cc = db * db * invT;
                float ea = __expf(a), ec = __expf(cc);
                float d  = cc - a;
                acc[j][0] += ea;
                acc[j][1] += ec;
                acc[j][2] = fmaf(ea, d, acc[j][2]);
                acc[j][3] = fmaf(ec, d, acc[j][3]);
            }
        }
        __syncthreads();   // protect ebp_s/bar_s before next chunk's staging
    }

    // ---- dcl partials: half-wave reductions, lanes 0 & 32 write ----
#pragma unroll
    for (int j = 0; j < 7; ++j) {
        float a0 = half_sum(acc[j][0]);
        float a1 = half_sum(acc[j][1]);
        float a2 = half_sum(acc[j][2]);
        float a3 = half_sum(acc[j][3]);
        if (c32 == 0) {
            const int row = wv * 14 + 2 * j + sub;
            float* qp = pdcl + (((size_t)row * BATCH + b) * NQ + q) * 4;
            qp[0] = a0; qp[1] = a1; qp[2] = a2; qp[3] = a3;
        }
    }
    // ---- dil block reduction (waves 2,3 contribute zeros) ----
    dss = wave_sum(dss); dts = wave_sum(dts);
    dt1 = wave_sum(dt1); dt2 = wave_sum(dt2);
    if (lane == 0) { redl[wv][0] = dss; redl[wv][1] = dts; redl[wv][2] = dt1; redl[wv][3] = dt2; }
    __syncthreads();
    if (t == 0) {
        float* qp = pdil + (size_t)bid * 4;
#pragma unroll
        for (int k = 0; k < 4; ++k)
            qp[k] = redl[0][k] + redl[1][k] + redl[2][k] + redl[3][k];
    }
}

// ---------------- finalize 1: per-(b,p) ratios, reduced per p-block --------
// grid = PN blocks, 256 threads (one per b). pdcl reads are fully coalesced:
// thread b reads 64 consecutive bytes at ((p*BATCH+b)*NQ)*16.
__global__ void __launch_bounds__(256) finalize1_kernel(const float* __restrict__ pdcl,
                                                        double* __restrict__ partial)
{
    __shared__ double sd[4];
    const int p = blockIdx.x, t = threadIdx.x, lane = t & 63, wv = t >> 6;
    const float* base = pdcl + ((size_t)p * BATCH + t) * NQ * 4;
    double A = 0.0, C = 0.0, T1 = 0.0, T2 = 0.0;
#pragma unroll
    for (int qq = 0; qq < NQ; ++qq) {
        float4 v = *(const float4*)(base + qq * 4);
        A += v.x; C += v.y; T1 += v.z; T2 += v.w;
    }
    double r = T2 / C - T1 / A;
    r = wave_sum_d(r);
    if (lane == 0) sd[wv] = r;
    __syncthreads();
    if (t == 0) partial[p] = sd[0] + sd[1] + sd[2] + sd[3];
}

// ---------------- finalize 2: combine p-partials + dil, emit outputs ------
__global__ void __launch_bounds__(256) finalize2_kernel(const double* __restrict__ partial,
                                                        const float* __restrict__ pdil,
                                                        float* __restrict__ out)
{
    __shared__ double sdc[4], sdl[4];
    const int t = threadIdx.x, lane = t & 63, wv = t >> 6;

    // dcl: sum the 56 per-p partials
    double vd = (t < PN) ? partial[t] : 0.0;

    // dil: thread t owns batch row b=t; combine NQ quarter-sums then ratio
    const float* base = pdil + (size_t)t * NQ * 4;
    double ss = 0.0, ts = 0.0, u1 = 0.0, u2 = 0.0;
#pragma unroll
    for (int qq = 0; qq < NQ; ++qq) {
        float4 v = *(const float4*)(base + qq * 4);
        ss += v.x; ts += v.y; u1 += v.z; u2 += v.w;
    }
    double vl = u2 / ts - u1 / ss;

    vd = wave_sum_d(vd); vl = wave_sum_d(vl);
    if (lane == 0) { sdc[wv] = vd; sdl[wv] = vl; }
    __syncthreads();
    if (t == 0) {
        const double kT2 = (double)KD_T * KD_T;
        out[0] = (float)((sdl[0] + sdl[1] + sdl[2] + sdl[3]) * (kT2 / DIM));
        out[1] = (float)((sdc[0] + sdc[1] + sdc[2] + sdc[3]) * (kT2 / DIM / PN));
    }
}

extern "C" void kernel_launch(void* const* d_in, const int* in_sizes, int n_in,
                              void* d_out, int out_size, void* d_ws, size_t ws_size,
                              hipStream_t stream) {
    const float* ebg = (const float*)d_in[0];
    const float* ebp = (const float*)d_in[1];
    // labels (d_in[2]) unused by the forward computation

    float*  pdcl    = (float*)d_ws;                                   // PN*BATCH*NQ*4 floats = 896 KB
    float*  pdil    = pdcl + (size_t)PN * BATCH * NQ * 4;             // NBLK*4 floats = 16 KB
    double* partial = (double*)(pdil + (size_t)NBLK * 4);             // PN doubles

    fused_kernel<<<NBLK, 256, 0, stream>>>(ebg, ebp, pdcl, pdil);
    finalize1_kernel<<<PN, 256, 0, stream>>>(pdcl, partial);
    finalize2_kernel<<<1, 256, 0, stream>>>(partial, pdil, (float*)d_out);
}